// Round 1
// baseline (11.471 us; speedup 1.0000x reference)
//
#include <hip/hip_runtime.h>

// SequenceClassifier_41790031790259
//
// Reference:
//   logits = h_last @ W_out.T + b_out        -> shape [B, 1]
//   return jax.nn.softmax(logits, axis=-1)   -> softmax over a single-element
//                                               axis == exactly 1.0 everywhere
//
// The entire RNN (input projection + 2048-step recurrence + output head) is
// dead code w.r.t. the output: for any finite inputs the result is
// ones((B, 1), float32). B = 128, so out_size = 128.
//
// The optimal kernel is therefore a single tiny dispatch writing 1.0f to the
// 128 output elements. Two waves (128 threads), one 4B store per lane.

__global__ void write_ones_kernel(float* __restrict__ out, int n) {
    int i = blockIdx.x * blockDim.x + threadIdx.x;
    if (i < n) {
        out[i] = 1.0f;
    }
}

extern "C" void kernel_launch(void* const* d_in, const int* in_sizes, int n_in,
                              void* d_out, int out_size, void* d_ws, size_t ws_size,
                              hipStream_t stream) {
    (void)d_in; (void)in_sizes; (void)n_in; (void)d_ws; (void)ws_size;
    float* out = (float*)d_out;
    const int threads = 128;
    const int blocks = (out_size + threads - 1) / threads;  // = 1 for out_size=128
    write_ones_kernel<<<blocks, threads, 0, stream>>>(out, out_size);
}